// Round 6
// baseline (8904.458 us; speedup 1.0000x reference)
//
#include <hip/hip_runtime.h>

using u8  = unsigned char;
using u16 = unsigned short;
using u32 = unsigned int;
typedef __attribute__((ext_vector_type(8))) short short8;   // 8 bf16 (MFMA A/B frag)
typedef __attribute__((ext_vector_type(4))) float f32x4;    // MFMA C/D frag

#define CAPL 320   // per-row candidate list capacity (expected ~193, sd 13)
#define QMIN 64    // static screen: q = round(32*v) >= 64  <=>  v >= 2.0
#define ECAP 1024  // per-block LDS emission buffer (expected ~386, sd 19)
#define RCAP 128   // refine subset capacity (expected ~45)

__device__ __forceinline__ float bf2f(u16 u) {
    union { u32 i; float f; } c; c.i = ((u32)u) << 16; return c.f;
}
__device__ __forceinline__ u16 f2bf(float f) {
    union { float f; u32 i; } c; c.f = f;
    u32 u = c.i + 0x7FFFu + ((c.i >> 16) & 1u);   // RNE; inputs are finite
    return (u16)(u >> 16);
}

// ---------------------------------------------------------------------------
// Kernel 0: Ap = bf16(x - b_dec), Wb = bf16(W_enc), Wd = bf16(W_dec), cnt = 0
// ---------------------------------------------------------------------------
__global__ __launch_bounds__(256) void prep_convert(const float* __restrict__ x,
                                                    const float* __restrict__ b_dec,
                                                    const float* __restrict__ W_enc,
                                                    const float* __restrict__ W_dec,
                                                    u16* __restrict__ Ap,
                                                    u16* __restrict__ Wb,
                                                    u16* __restrict__ Wd,
                                                    u32* __restrict__ cnt) {
    int i = blockIdx.x * 256 + threadIdx.x;     // grid covers 5*2^20 exactly
    if (i < 4096) cnt[i] = 0;
    if (i < 4096 * 256) {
        Ap[i] = f2bf(x[i] - b_dec[i & 255]);
    } else if (i < 3 * 1048576) {
        int j = i - 1048576;
        Wb[j] = f2bf(W_enc[j]);
    } else {
        int j = i - 3 * 1048576;
        Wd[j] = f2bf(W_dec[j]);
    }
}

// ---------------------------------------------------------------------------
// Kernel 1: encode GEMM; epilogue emits candidates (q >= QMIN) via
// wave-aggregated LDS staging: per-thread count -> wave prefix scan -> ONE
// LDS atomic per wave -> slot writes; then per-row offsets -> ONE global
// atomic per (row, block) -> contiguous list writes.
// M=4096, N=8192, K=256. NT, 128x128 tile, 4 waves of 64x64, 16x16x32 MFMA.
// ---------------------------------------------------------------------------
__global__ __launch_bounds__(256) void encode_gemm(const u16* __restrict__ A,
                                                   const u16* __restrict__ W,
                                                   const float* __restrict__ b_enc,
                                                   u32* __restrict__ cnt,
                                                   u32* __restrict__ list) {
    const int tid  = threadIdx.x;
    const int lane = tid & 63;
    const int wave = tid >> 6;
    const int wm = wave & 1, wn = wave >> 1;
    const int bm0 = blockIdx.y * 128;             // block row base
    const int m0  = bm0 + wm * 64;
    const int n0  = blockIdx.x * 128 + wn * 64;
    const int r15 = lane & 15;            // m (A) / n (B) within 16-frag
    const int kq  = (lane >> 4) * 8;      // k offset within K=32 chunk

    __shared__ u32 s_n;
    __shared__ u32 s_ebuf[ECAP];   // entry: (rowl<<21)|(n<<8)|q
    __shared__ u8  s_eofs[ECAP];   // within-(row,block) offset (<=128, fits u8)
    __shared__ u32 l_cnt[128];
    __shared__ u32 l_base[128];

    if (tid == 0) s_n = 0;
    if (tid < 128) l_cnt[tid] = 0;
    __syncthreads();

    f32x4 acc[4][4] = {};
    const u16* Abase = A + (size_t)(m0 + r15) * 256 + kq;
    const u16* Wbase = W + (size_t)(n0 + r15) * 256 + kq;

    for (int k0 = 0; k0 < 256; k0 += 32) {
        short8 a[4], b[4];
#pragma unroll
        for (int i = 0; i < 4; i++)
            a[i] = *(const short8*)(Abase + i * 16 * 256 + k0);
#pragma unroll
        for (int j = 0; j < 4; j++)
            b[j] = *(const short8*)(Wbase + j * 16 * 256 + k0);
#pragma unroll
        for (int i = 0; i < 4; i++)
#pragma unroll
            for (int j = 0; j < 4; j++)
                acc[i][j] = __builtin_amdgcn_mfma_f32_16x16x32_bf16(a[i], b[j], acc[i][j], 0, 0, 0);
    }

    // bias per j (C/D layout: col(n) = lane&15, row(m) = (lane>>4)*4 + reg)
    float bias[4];
#pragma unroll
    for (int j = 0; j < 4; j++) bias[j] = b_enc[n0 + j * 16 + r15];

    // --- pass 1: per-thread candidate count ---------------------------------
    int my_n = 0;
#pragma unroll
    for (int j = 0; j < 4; j++)
#pragma unroll
        for (int i = 0; i < 4; i++)
#pragma unroll
            for (int rq = 0; rq < 4; rq++) {
                float v = acc[i][j][rq] + bias[j];
                my_n += ((int)(v * 32.f + 0.5f) >= QMIN);
            }

    // --- wave prefix scan + one LDS atomic per wave -------------------------
    int pv = my_n;
#pragma unroll
    for (int d = 1; d < 64; d <<= 1) {
        int t = __shfl_up(pv, d);
        if (lane >= d) pv += t;
    }
    u32 base;
    if (lane == 63) base = atomicAdd(&s_n, (u32)pv);  // lane63 pv == wave total
    base = __shfl((int)base, 63);
    u32 off = base + (u32)(pv - my_n);

    // --- pass 2: write entries at scanned offsets ---------------------------
#pragma unroll
    for (int j = 0; j < 4; j++)
#pragma unroll
        for (int i = 0; i < 4; i++) {
            int rowl0 = wm * 64 + i * 16 + (lane >> 4) * 4;   // local row
#pragma unroll
            for (int rq = 0; rq < 4; rq++) {
                float v = acc[i][j][rq] + bias[j];
                int q = (int)(v * 32.f + 0.5f);
                if (q >= QMIN) {
                    if (q > 255) q = 255;
                    u32 rowl = (u32)(rowl0 + rq);
                    int n = n0 + j * 16 + r15;
                    u32 e = (rowl << 21) | ((u32)n << 8) | (u32)q;
                    if (off < ECAP) {
                        s_ebuf[off] = e;
                    } else {                       // never expected: direct spill
                        u32 g = atomicAdd(&cnt[bm0 + rowl], 1u);
                        if (g < CAPL) list[(size_t)(bm0 + rowl) * CAPL + g] = e & 0x1FFFFFu;
                    }
                    off++;
                }
            }
        }
    __syncthreads();

    int ne = (int)s_n; if (ne > ECAP) ne = ECAP;
    // Phase A: within-row offsets via LDS atomics (spread over 128 addresses)
    for (int i = tid; i < ne; i += 256)
        s_eofs[i] = (u8)atomicAdd(&l_cnt[s_ebuf[i] >> 21], 1u);
    __syncthreads();
    // Phase B: one global reservation per (row, block)
    if (tid < 128 && l_cnt[tid] > 0)
        l_base[tid] = atomicAdd(&cnt[bm0 + tid], l_cnt[tid]);
    __syncthreads();
    // Phase C: contiguous slot writes
    for (int i = tid; i < ne; i += 256) {
        u32 e = s_ebuf[i];
        u32 rowl = e >> 21;
        u32 slot = l_base[rowl] + (u32)s_eofs[i];
        if (slot < CAPL) list[(size_t)(bm0 + rowl) * CAPL + slot] = e & 0x1FFFFFu;
    }
}

// ---------------------------------------------------------------------------
// Kernel 2: per row — list -> q-hist -> t32 -> compact refine subset
// {q >= t32-2} -> exact fp64 refine -> exact top-32 (val desc, idx asc) ->
// decode with bf16 W_dec. Exact fallback if screen invalid (never expected).
// ---------------------------------------------------------------------------
__global__ __launch_bounds__(256) void select_decode(const u32* __restrict__ cnt,
                                                     const u32* __restrict__ list,
                                                     const float* __restrict__ x,
                                                     const float* __restrict__ W_enc,
                                                     const float* __restrict__ b_enc,
                                                     const u16* __restrict__ Wd,
                                                     const float* __restrict__ b_dec,
                                                     float* __restrict__ out) {
    const int r    = blockIdx.x;
    const int tid  = threadIdx.x;
    const int lane = tid & 63;
    const int wave = tid >> 6;
    const int grp  = tid >> 4;     // 16 groups of 16 lanes (refine)
    const int l16  = tid & 15;

    __shared__ float s_sae[256];
    __shared__ u32   hist[256];
    __shared__ int   wtot[4];
    __shared__ int   s_t32;
    __shared__ u32   s_nref;
    __shared__ int   cidx[CAPL];
    __shared__ int   cq[CAPL];      // fallback reuses as red_i
    __shared__ float cval[CAPL];    // fallback reuses as red_v
    __shared__ short rsel[RCAP];
    __shared__ float sel_val[32];
    __shared__ int   sel_idx[32];

    s_sae[tid] = x[(size_t)r * 256 + tid] - b_dec[tid];
    hist[tid] = 0;
    if (tid == 0) { s_t32 = -1; s_nref = 0; }
    if (tid < 32) { sel_val[tid] = 0.f; sel_idx[tid] = 0; }
    __syncthreads();

    const int m_all = (int)cnt[r];
    const int m = m_all < CAPL ? m_all : CAPL;

    // --- load candidate list, histogram q ------------------------------------
    for (int i = tid; i < m; i += 256) {
        u32 p = list[(size_t)r * CAPL + i];
        int q = (int)(p & 255u);
        cq[i] = q; cidx[i] = (int)(p >> 8);
        atomicAdd(&hist[q], 1u);
    }
    __syncthreads();

    // --- suffix scan: t32 = max{b : count(q >= b) >= 32} ---------------------
    {
        int c = (int)hist[tid];
        int s = c;
#pragma unroll
        for (int off = 1; off < 64; off <<= 1) {
            int v = __shfl_down(s, off);
            if (lane + off < 64) s += v;
        }
        if (lane == 0) wtot[wave] = s;
        __syncthreads();
        int hisum = 0;
        for (int ww = wave + 1; ww < 4; ww++) hisum += wtot[ww];
        int S = s + hisum;
        if (S >= 32 && (S - c) < 32) s_t32 = tid;   // unique transition bin
    }
    __syncthreads();

    const int qref = s_t32 - 2;   // true top-32 provably within {q >= qref}
    // --- compact refine subset ----------------------------------------------
    for (int i = tid; i < m; i += 256) {
        if (cq[i] >= qref) {
            u32 p = atomicAdd(&s_nref, 1u);
            if (p < RCAP) rsel[p] = (short)i;
        }
    }
    __syncthreads();
    const int nref = (int)s_nref;

    // valid screen: no overflow anywhere, t32-2 >= QMIN (membership proof)
    const bool fb = (m_all > CAPL) || (s_t32 < QMIN + 2) || (nref > RCAP);

    if (!fb) {
        // --- exact refine (fp64): 2 candidates per 16-lane group per pass ---
        for (int t0 = 0; t0 < nref; t0 += 32) {
            int cA = t0 + grp, cB = t0 + grp + 16;
            float4 wA[4], wB[4];
            int iA = -1, iB = -1;
            if (cA < nref) {
                iA = cidx[rsel[cA]];
                const float4* wr = (const float4*)(W_enc + (size_t)iA * 256 + l16 * 16);
#pragma unroll
                for (int u = 0; u < 4; u++) wA[u] = wr[u];
            }
            if (cB < nref) {
                iB = cidx[rsel[cB]];
                const float4* wr = (const float4*)(W_enc + (size_t)iB * 256 + l16 * 16);
#pragma unroll
                for (int u = 0; u < 4; u++) wB[u] = wr[u];
            }
            if (iA >= 0) {
                double s = 0.0;
#pragma unroll
                for (int u = 0; u < 4; u++) {
                    const float* sp = &s_sae[l16 * 16 + u * 4];
                    s += (double)wA[u].x * (double)sp[0] + (double)wA[u].y * (double)sp[1]
                       + (double)wA[u].z * (double)sp[2] + (double)wA[u].w * (double)sp[3];
                }
#pragma unroll
                for (int off = 8; off; off >>= 1) s += __shfl_down(s, off, 16);
                if (l16 == 0) {
                    float f = (float)(s + (double)b_enc[iA]);
                    cval[rsel[cA]] = f > 0.f ? f : 0.f;
                }
            }
            if (iB >= 0) {
                double s = 0.0;
#pragma unroll
                for (int u = 0; u < 4; u++) {
                    const float* sp = &s_sae[l16 * 16 + u * 4];
                    s += (double)wB[u].x * (double)sp[0] + (double)wB[u].y * (double)sp[1]
                       + (double)wB[u].z * (double)sp[2] + (double)wB[u].w * (double)sp[3];
                }
#pragma unroll
                for (int off = 8; off; off >>= 1) s += __shfl_down(s, off, 16);
                if (l16 == 0) {
                    float f = (float)(s + (double)b_enc[iB]);
                    cval[rsel[cB]] = f > 0.f ? f : 0.f;
                }
            }
        }
        __syncthreads();

        // --- exact top-32 among refined by (val desc, idx asc) --------------
        for (int k = tid; k < nref; k += 256) {
            int ci = rsel[k];
            float vi = cval[ci];
            int   ii = cidx[ci];
            int rank = 0;
            for (int j = 0; j < nref; j++) {
                int cj = rsel[j];
                float vj = cval[cj];
                rank += (vj > vi) || (vj == vi && cidx[cj] < ii);
            }
            if (rank < 32) { sel_val[rank] = vi; sel_idx[rank] = ii; }
        }
        __syncthreads();
    } else {
        // --- guaranteed-exact fallback: full-row top-32 from scratch --------
        float* red_v = cval;   // reuse LDS
        int*   red_i = cq;
        u32 taken = 0;
        for (int k = 0; k < 32; k++) {
            float bv = -1.f; int bi = 1 << 30;
            for (int j = 0; j < 32; j++) {
                if ((taken >> j) & 1u) continue;
                int h = tid + 256 * j;
                const float4* wr = (const float4*)(W_enc + (size_t)h * 256);
                double s = 0.0;
                for (int u = 0; u < 64; u++) {
                    float4 wv = wr[u];
                    const float* sp = &s_sae[u * 4];
                    s += (double)wv.x * (double)sp[0] + (double)wv.y * (double)sp[1]
                       + (double)wv.z * (double)sp[2] + (double)wv.w * (double)sp[3];
                }
                float v = (float)(s + (double)b_enc[h]);
                v = v > 0.f ? v : 0.f;
                if (v > bv) { bv = v; bi = h; }   // j asc => smallest idx on tie
            }
            red_v[tid] = bv; red_i[tid] = bi;
            __syncthreads();
            for (int off = 128; off; off >>= 1) {
                if (tid < off) {
                    float v2 = red_v[tid + off]; int i2 = red_i[tid + off];
                    if (v2 > red_v[tid] || (v2 == red_v[tid] && i2 < red_i[tid])) {
                        red_v[tid] = v2; red_i[tid] = i2;
                    }
                }
                __syncthreads();
            }
            int win = red_i[0];
            if (tid == 0) { sel_val[k] = red_v[0]; sel_idx[k] = win; }
            if ((win & 255) == tid) taken |= 1u << (win >> 8);
            __syncthreads();
        }
    }

    // --- decode: out[r] = b_dec + sum_k z_k * bf16(W_dec)[idx_k] ------------
    u16 wv[32];
#pragma unroll
    for (int k = 0; k < 32; k++)
        wv[k] = Wd[(size_t)sel_idx[k] * 256 + tid];   // 32 independent loads
    float acc = b_dec[tid];
#pragma unroll
    for (int k = 0; k < 32; k++)
        acc += sel_val[k] * bf2f(wv[k]);
    out[(size_t)r * 256 + tid] = acc;
}

// ---------------------------------------------------------------------------
extern "C" void kernel_launch(void* const* d_in, const int* in_sizes, int n_in,
                              void* d_out, int out_size, void* d_ws, size_t ws_size,
                              hipStream_t stream) {
    const float* x     = (const float*)d_in[0];   // [4096,256] f32
    const float* W_enc = (const float*)d_in[1];   // [8192,256] f32
    const float* b_enc = (const float*)d_in[2];   // [8192]     f32
    const float* W_dec = (const float*)d_in[3];   // [8192,256] f32
    const float* b_dec = (const float*)d_in[4];   // [256]      f32
    float* out = (float*)d_out;                   // [4096,256] f32

    u32* cnt  = (u32*)d_ws;                          // 16 KB per-row counters
    u32* list = cnt + 4096;                          // 5.2 MB candidate lists
    u16* Ap   = (u16*)(list + (size_t)4096 * CAPL);  // 2 MB bf16(x - b_dec)
    u16* Wb   = Ap + (size_t)4096 * 256;             // 4 MB bf16(W_enc)
    u16* Wd   = Wb + (size_t)8192 * 256;             // 4 MB bf16(W_dec)

    prep_convert<<<20480, 256, 0, stream>>>(x, b_dec, W_enc, W_dec, Ap, Wb, Wd, cnt);
    encode_gemm<<<dim3(64, 32), 256, 0, stream>>>(Ap, Wb, b_enc, cnt, list);
    select_decode<<<4096, 256, 0, stream>>>(cnt, list, x, W_enc, b_enc, Wd, b_dec, out);
}

// Round 7
// 208.710 us; speedup vs baseline: 42.6643x; 42.6643x over previous
//
#include <hip/hip_runtime.h>

using u8  = unsigned char;
using u16 = unsigned short;
using u32 = unsigned int;
typedef __attribute__((ext_vector_type(8))) short short8;   // 8 bf16 (MFMA A/B frag)
typedef __attribute__((ext_vector_type(4))) float f32x4;    // MFMA C/D frag

#define CAPL 512   // per-row list capacity; m_all=8192*Q(2/sigma), sigma=|x_r|/16:
                   // overflow needs sigma>=1.31 = +7sd of chi2_256 -> never
#define QMIN 64    // static screen: q = round(32*v) >= 64  <=>  v >= 2.0
#define ECAP 1024  // per-block LDS emission buffer (expected ~373, sd ~20)
#define RCAP 128   // refine subset capacity (expected ~45, quantile-invariant)

__device__ __forceinline__ float bf2f(u16 u) {
    union { u32 i; float f; } c; c.i = ((u32)u) << 16; return c.f;
}
__device__ __forceinline__ u16 f2bf(float f) {
    union { float f; u32 i; } c; c.f = f;
    u32 u = c.i + 0x7FFFu + ((c.i >> 16) & 1u);   // RNE; inputs are finite
    return (u16)(u >> 16);
}

// ---------------------------------------------------------------------------
// Kernel 0: Ap = bf16(x - b_dec), Wb = bf16(W_enc), Wd = bf16(W_dec), cnt = 0
// ---------------------------------------------------------------------------
__global__ __launch_bounds__(256) void prep_convert(const float* __restrict__ x,
                                                    const float* __restrict__ b_dec,
                                                    const float* __restrict__ W_enc,
                                                    const float* __restrict__ W_dec,
                                                    u16* __restrict__ Ap,
                                                    u16* __restrict__ Wb,
                                                    u16* __restrict__ Wd,
                                                    u32* __restrict__ cnt) {
    int i = blockIdx.x * 256 + threadIdx.x;     // grid covers 5*2^20 exactly
    if (i < 4096) cnt[i] = 0;
    if (i < 4096 * 256) {
        Ap[i] = f2bf(x[i] - b_dec[i & 255]);
    } else if (i < 3 * 1048576) {
        int j = i - 1048576;
        Wb[j] = f2bf(W_enc[j]);
    } else {
        int j = i - 3 * 1048576;
        Wd[j] = f2bf(W_dec[j]);
    }
}

// ---------------------------------------------------------------------------
// Kernel 1: encode GEMM; epilogue emits candidates (q >= QMIN) via
// wave-aggregated LDS staging: per-thread count -> wave prefix scan -> ONE
// LDS atomic per wave -> slot writes; then per-row offsets -> ONE global
// atomic per (row, block) -> contiguous list writes.
// ---------------------------------------------------------------------------
__global__ __launch_bounds__(256) void encode_gemm(const u16* __restrict__ A,
                                                   const u16* __restrict__ W,
                                                   const float* __restrict__ b_enc,
                                                   u32* __restrict__ cnt,
                                                   u32* __restrict__ list) {
    const int tid  = threadIdx.x;
    const int lane = tid & 63;
    const int wave = tid >> 6;
    const int wm = wave & 1, wn = wave >> 1;
    const int bm0 = blockIdx.y * 128;             // block row base
    const int m0  = bm0 + wm * 64;
    const int n0  = blockIdx.x * 128 + wn * 64;
    const int r15 = lane & 15;            // m (A) / n (B) within 16-frag
    const int kq  = (lane >> 4) * 8;      // k offset within K=32 chunk

    __shared__ u32 s_n;
    __shared__ u32 s_ebuf[ECAP];   // entry: (rowl<<21)|(n<<8)|q
    __shared__ u8  s_eofs[ECAP];   // within-(row,block) offset (<128, fits u8)
    __shared__ u32 l_cnt[128];
    __shared__ u32 l_base[128];

    if (tid == 0) s_n = 0;
    if (tid < 128) l_cnt[tid] = 0;
    __syncthreads();

    f32x4 acc[4][4] = {};
    const u16* Abase = A + (size_t)(m0 + r15) * 256 + kq;
    const u16* Wbase = W + (size_t)(n0 + r15) * 256 + kq;

    for (int k0 = 0; k0 < 256; k0 += 32) {
        short8 a[4], b[4];
#pragma unroll
        for (int i = 0; i < 4; i++)
            a[i] = *(const short8*)(Abase + i * 16 * 256 + k0);
#pragma unroll
        for (int j = 0; j < 4; j++)
            b[j] = *(const short8*)(Wbase + j * 16 * 256 + k0);
#pragma unroll
        for (int i = 0; i < 4; i++)
#pragma unroll
            for (int j = 0; j < 4; j++)
                acc[i][j] = __builtin_amdgcn_mfma_f32_16x16x32_bf16(a[i], b[j], acc[i][j], 0, 0, 0);
    }

    // C/D layout: col(n) = lane&15, row(m) = (lane>>4)*4 + reg   [m89-verified]
    float bias[4];
#pragma unroll
    for (int j = 0; j < 4; j++) bias[j] = b_enc[n0 + j * 16 + r15];

    // --- pass 1: per-thread candidate count ---------------------------------
    int my_n = 0;
#pragma unroll
    for (int j = 0; j < 4; j++)
#pragma unroll
        for (int i = 0; i < 4; i++)
#pragma unroll
            for (int rq = 0; rq < 4; rq++) {
                float v = acc[i][j][rq] + bias[j];
                my_n += ((int)(v * 32.f + 0.5f) >= QMIN);
            }

    // --- wave prefix scan + one LDS atomic per wave -------------------------
    int pv = my_n;
#pragma unroll
    for (int d = 1; d < 64; d <<= 1) {
        int t = __shfl_up(pv, d);
        if (lane >= d) pv += t;
    }
    u32 base;
    if (lane == 63) base = atomicAdd(&s_n, (u32)pv);  // lane63 pv == wave total
    base = __shfl((int)base, 63);
    u32 off = base + (u32)(pv - my_n);

    // --- pass 2: write entries at scanned offsets ---------------------------
#pragma unroll
    for (int j = 0; j < 4; j++)
#pragma unroll
        for (int i = 0; i < 4; i++) {
            int rowl0 = wm * 64 + i * 16 + (lane >> 4) * 4;   // local row
#pragma unroll
            for (int rq = 0; rq < 4; rq++) {
                float v = acc[i][j][rq] + bias[j];
                int q = (int)(v * 32.f + 0.5f);
                if (q >= QMIN) {
                    if (q > 255) q = 255;
                    u32 rowl = (u32)(rowl0 + rq);
                    int n = n0 + j * 16 + r15;
                    u32 e = (rowl << 21) | ((u32)n << 8) | (u32)q;
                    if (off < ECAP) {
                        s_ebuf[off] = e;
                    } else {                       // never expected: direct spill
                        u32 g = atomicAdd(&cnt[bm0 + rowl], 1u);
                        if (g < CAPL) list[(size_t)(bm0 + rowl) * CAPL + g] = e & 0x1FFFFFu;
                    }
                    off++;
                }
            }
        }
    __syncthreads();

    int ne = (int)s_n; if (ne > ECAP) ne = ECAP;
    // Phase A: within-row offsets via LDS atomics (spread over 128 addresses)
    for (int i = tid; i < ne; i += 256)
        s_eofs[i] = (u8)atomicAdd(&l_cnt[s_ebuf[i] >> 21], 1u);
    __syncthreads();
    // Phase B: one global reservation per (row, block)
    if (tid < 128 && l_cnt[tid] > 0)
        l_base[tid] = atomicAdd(&cnt[bm0 + tid], l_cnt[tid]);
    __syncthreads();
    // Phase C: contiguous slot writes
    for (int i = tid; i < ne; i += 256) {
        u32 e = s_ebuf[i];
        u32 rowl = e >> 21;
        u32 slot = l_base[rowl] + (u32)s_eofs[i];
        if (slot < CAPL) list[(size_t)(bm0 + rowl) * CAPL + slot] = e & 0x1FFFFFu;
    }
}

// ---------------------------------------------------------------------------
// Kernel 2: per row — list -> q-hist -> t32 -> compact refine subset
// {q >= t32-2} -> exact fp64 refine -> exact top-32 (val desc, idx asc) ->
// decode with bf16 W_dec. CHEAP exact fallback (2 streaming passes) if the
// screen is invalid (never expected, but cheap now).
// ---------------------------------------------------------------------------
__global__ __launch_bounds__(256) void select_decode(const u32* __restrict__ cnt,
                                                     const u32* __restrict__ list,
                                                     const float* __restrict__ x,
                                                     const float* __restrict__ W_enc,
                                                     const float* __restrict__ b_enc,
                                                     const u16* __restrict__ Wd,
                                                     const float* __restrict__ b_dec,
                                                     float* __restrict__ out) {
    const int r    = blockIdx.x;
    const int tid  = threadIdx.x;
    const int lane = tid & 63;
    const int wave = tid >> 6;
    const int grp  = tid >> 4;     // 16 groups of 16 lanes
    const int l16  = tid & 15;

    __shared__ float s_sae[256];
    __shared__ u32   hist[256];
    __shared__ int   wtot[4];
    __shared__ int   s_t32;
    __shared__ u32   s_nref;
    __shared__ int   cidx[CAPL];
    __shared__ int   cq[CAPL];
    __shared__ float cval[CAPL];
    __shared__ short rsel[RCAP];
    __shared__ float sel_val[32];
    __shared__ int   sel_idx[32];

    s_sae[tid] = x[(size_t)r * 256 + tid] - b_dec[tid];
    hist[tid] = 0;
    if (tid == 0) { s_t32 = -1; s_nref = 0; }
    if (tid < 32) { sel_val[tid] = 0.f; sel_idx[tid] = 0; }
    __syncthreads();

    // t32 = max{b : count(q >= b) >= 32} from hist; -1 if < 32 entries
    auto find_t32 = [&]() {
        int c = (int)hist[tid];
        int s = c;
#pragma unroll
        for (int off = 1; off < 64; off <<= 1) {
            int v = __shfl_down(s, off);
            if (lane + off < 64) s += v;
        }
        if (lane == 0) wtot[wave] = s;
        __syncthreads();
        int hisum = 0;
        for (int ww = wave + 1; ww < 4; ww++) hisum += wtot[ww];
        int S = s + hisum;
        if (S >= 32 && (S - c) < 32) s_t32 = tid;   // unique transition bin
        __syncthreads();
    };
    // exact fp64 dot of s_sae with W_enc[col]; result valid on l16==0
    auto exact_col = [&](int col) -> double {
        const float4* wr = (const float4*)(W_enc + (size_t)col * 256 + l16 * 16);
        double s = 0.0;
#pragma unroll
        for (int u = 0; u < 4; u++) {
            float4 wv = wr[u];
            const float* sp = &s_sae[l16 * 16 + u * 4];
            s += (double)wv.x * (double)sp[0] + (double)wv.y * (double)sp[1]
               + (double)wv.z * (double)sp[2] + (double)wv.w * (double)sp[3];
        }
#pragma unroll
        for (int off = 8; off; off >>= 1) s += __shfl_down(s, off, 16);
        return s;
    };

    const int m_all = (int)cnt[r];
    const int m = m_all < CAPL ? m_all : CAPL;

    // --- load candidate list, histogram q ------------------------------------
    for (int i = tid; i < m; i += 256) {
        u32 p = list[(size_t)r * CAPL + i];
        int q = (int)(p & 255u);
        cq[i] = q; cidx[i] = (int)(p >> 8);
        atomicAdd(&hist[q], 1u);
    }
    __syncthreads();
    find_t32();

    const int qref = s_t32 - 2;   // true top-32 provably within {q >= qref}
    // --- compact refine subset ----------------------------------------------
    for (int i = tid; i < m; i += 256) {
        if (cq[i] >= qref) {
            u32 p = atomicAdd(&s_nref, 1u);
            if (p < RCAP) rsel[p] = (short)i;
        }
    }
    __syncthreads();
    const int nref = (int)s_nref;

    // valid screen: no overflow anywhere, t32-2 >= QMIN (membership proof)
    const bool fb = (m_all > CAPL) || (s_t32 < QMIN + 2) || (nref > RCAP);

    if (!fb) {
        // --- exact refine (fp64): 2 candidates per 16-lane group per pass ---
        for (int t0 = 0; t0 < nref; t0 += 32) {
            int cA = t0 + grp, cB = t0 + grp + 16;
            if (cA < nref) {
                int iA = cidx[rsel[cA]];
                double s = exact_col(iA);
                if (l16 == 0) {
                    float f = (float)(s + (double)b_enc[iA]);
                    cval[rsel[cA]] = f > 0.f ? f : 0.f;
                }
            }
            if (cB < nref) {
                int iB = cidx[rsel[cB]];
                double s = exact_col(iB);
                if (l16 == 0) {
                    float f = (float)(s + (double)b_enc[iB]);
                    cval[rsel[cB]] = f > 0.f ? f : 0.f;
                }
            }
        }
        __syncthreads();

        // --- exact top-32 among refined by (val desc, idx asc) --------------
        for (int k = tid; k < nref; k += 256) {
            int ci = rsel[k];
            float vi = cval[ci];
            int   ii = cidx[ci];
            int rank = 0;
            for (int j = 0; j < nref; j++) {
                int cj = rsel[j];
                float vj = cval[cj];
                rank += (vj > vi) || (vj == vi && cidx[cj] < ii);
            }
            if (rank < 32) { sel_val[rank] = vi; sel_idx[rank] = ii; }
        }
        __syncthreads();
    } else {
        // --- CHEAP exact fallback: 2 streaming passes over all 8192 cols ----
        hist[tid] = 0;
        if (tid == 0) { s_t32 = -1; s_nref = 0; }
        __syncthreads();
        // pass 1: exact values -> q histogram (bins >= 1)
        for (int it = 0; it < 512; it++) {
            int col = it * 16 + grp;
            double s = exact_col(col);
            if (l16 == 0) {
                float f = (float)(s + (double)b_enc[col]);
                f = f > 0.f ? f : 0.f;
                int q = (int)(f * 32.f + 0.5f); if (q > 255) q = 255;
                if (q >= 1) atomicAdd(&hist[q], 1u);
            }
        }
        __syncthreads();
        find_t32();
        int qlo = s_t32 >= 3 ? s_t32 - 2 : 1;
        // pass 2: gather {q >= qlo} with exact values (retry tighter if huge)
        for (int pass = 0; pass < 2; pass++) {
            for (int it = 0; it < 512; it++) {
                int col = it * 16 + grp;
                double s = exact_col(col);
                if (l16 == 0) {
                    float f = (float)(s + (double)b_enc[col]);
                    f = f > 0.f ? f : 0.f;
                    int q = (int)(f * 32.f + 0.5f); if (q > 255) q = 255;
                    if (q >= qlo) {
                        u32 p = atomicAdd(&s_nref, 1u);
                        if (p < CAPL) { cidx[p] = col; cval[p] = f; }
                    }
                }
            }
            __syncthreads();
            if ((int)s_nref <= CAPL) break;
            if (tid == 0) s_nref = 0;
            qlo = s_t32 > 0 ? s_t32 : 1;
            __syncthreads();
        }
        int nf = (int)s_nref; if (nf > CAPL) nf = CAPL;
        for (int k = tid; k < nf; k += 256) {
            float vi = cval[k]; int ii = cidx[k]; int rank = 0;
            for (int j = 0; j < nf; j++)
                rank += (cval[j] > vi) || (cval[j] == vi && cidx[j] < ii);
            if (rank < 32) { sel_val[rank] = vi; sel_idx[rank] = ii; }
        }
        __syncthreads();
    }

    // --- decode: out[r] = b_dec + sum_k z_k * bf16(W_dec)[idx_k] ------------
    u16 wv[32];
#pragma unroll
    for (int k = 0; k < 32; k++)
        wv[k] = Wd[(size_t)sel_idx[k] * 256 + tid];   // 32 independent loads
    float acc = b_dec[tid];
#pragma unroll
    for (int k = 0; k < 32; k++)
        acc += sel_val[k] * bf2f(wv[k]);
    out[(size_t)r * 256 + tid] = acc;
}

// ---------------------------------------------------------------------------
extern "C" void kernel_launch(void* const* d_in, const int* in_sizes, int n_in,
                              void* d_out, int out_size, void* d_ws, size_t ws_size,
                              hipStream_t stream) {
    const float* x     = (const float*)d_in[0];   // [4096,256] f32
    const float* W_enc = (const float*)d_in[1];   // [8192,256] f32
    const float* b_enc = (const float*)d_in[2];   // [8192]     f32
    const float* W_dec = (const float*)d_in[3];   // [8192,256] f32
    const float* b_dec = (const float*)d_in[4];   // [256]      f32
    float* out = (float*)d_out;                   // [4096,256] f32

    u32* cnt  = (u32*)d_ws;                          // 16 KB per-row counters
    u32* list = cnt + 4096;                          // 8 MB candidate lists
    u16* Ap   = (u16*)(list + (size_t)4096 * CAPL);  // 2 MB bf16(x - b_dec)
    u16* Wb   = Ap + (size_t)4096 * 256;             // 4 MB bf16(W_enc)
    u16* Wd   = Wb + (size_t)8192 * 256;             // 4 MB bf16(W_dec)

    prep_convert<<<20480, 256, 0, stream>>>(x, b_dec, W_enc, W_dec, Ap, Wb, Wd, cnt);
    encode_gemm<<<dim3(64, 32), 256, 0, stream>>>(Ap, Wb, b_enc, cnt, list);
    select_decode<<<4096, 256, 0, stream>>>(cnt, list, x, W_enc, b_enc, Wd, b_dec, out);
}

// Round 8
// 167.844 us; speedup vs baseline: 53.0518x; 1.2435x over previous
//
#include <hip/hip_runtime.h>

using u8  = unsigned char;
using u16 = unsigned short;
using u32 = unsigned int;
typedef __attribute__((ext_vector_type(8))) short short8;   // 8 bf16 (MFMA A/B frag)
typedef __attribute__((ext_vector_type(4))) float f32x4;    // MFMA C/D frag

#define CAPL 512   // per-row list capacity; overflow needs sigma>=1.31 (+7sd) -> never
#define QMIN 64    // static screen: q = round(32*v) >= 64  <=>  v >= 2.0
#define ECAP 1024  // per-block LDS emission buffer (expected ~373, sd ~20)
#define RCAP 128   // refine subset capacity (expected ~45, quantile-invariant)

__device__ __forceinline__ float bf2f(u16 u) {
    union { u32 i; float f; } c; c.i = ((u32)u) << 16; return c.f;
}
__device__ __forceinline__ u16 f2bf(float f) {
    union { float f; u32 i; } c; c.f = f;
    u32 u = c.i + 0x7FFFu + ((c.i >> 16) & 1u);   // RNE; inputs are finite
    return (u16)(u >> 16);
}

// ---------------------------------------------------------------------------
// Kernel 0: build FRAGMENT-SWIZZLED bf16 operands + bf16 W_dec + zero cnt.
// Swizzle: tile t=(mt*8+kt); lane l holds 8 bf16 at (row=16*mt+(l&15),
// k=32*kt+(l>>4)*8+j) stored at offset (t*64+l)*8 — so encode_gemm's frag
// loads are base+lane*16B, perfectly coalesced (1KB/wave/instruction).
// ---------------------------------------------------------------------------
__global__ __launch_bounds__(256) void prep_convert(const float* __restrict__ x,
                                                    const float* __restrict__ b_dec,
                                                    const float* __restrict__ W_enc,
                                                    const float* __restrict__ W_dec,
                                                    u16* __restrict__ Ap,
                                                    u16* __restrict__ Wb,
                                                    u16* __restrict__ Wd,
                                                    u32* __restrict__ cnt) {
    int i = blockIdx.x * 256 + threadIdx.x;     // grid = 2576 blocks exactly
    if (i < 131072) {                            // A: 256 mt x 8 kt tiles
        int lane = i & 63, t = i >> 6;
        int mt = t >> 3, kt = t & 7;
        int m = mt * 16 + (lane & 15);
        int k = kt * 32 + (lane >> 4) * 8;
        const float* xs = x + (size_t)m * 256 + k;
        const float* bd = b_dec + k;
        u32 o[4];
#pragma unroll
        for (int j = 0; j < 4; j++) {
            u16 lo = f2bf(xs[2*j]   - bd[2*j]);
            u16 hi = f2bf(xs[2*j+1] - bd[2*j+1]);
            o[j] = (u32)lo | ((u32)hi << 16);
        }
        *(uint4*)(Ap + (size_t)i * 8) = make_uint4(o[0], o[1], o[2], o[3]);
    } else if (i < 393216) {                     // W_enc: 512 nt x 8 kt tiles
        int j0 = i - 131072;
        int lane = j0 & 63, t = j0 >> 6;
        int nt = t >> 3, kt = t & 7;
        int n = nt * 16 + (lane & 15);
        int k = kt * 32 + (lane >> 4) * 8;
        const float* ws = W_enc + (size_t)n * 256 + k;
        u32 o[4];
#pragma unroll
        for (int j = 0; j < 4; j++) {
            u16 lo = f2bf(ws[2*j]);
            u16 hi = f2bf(ws[2*j+1]);
            o[j] = (u32)lo | ((u32)hi << 16);
        }
        *(uint4*)(Wb + (size_t)j0 * 8) = make_uint4(o[0], o[1], o[2], o[3]);
    } else if (i < 655360) {                     // W_dec: plain bf16, 8/thread
        int j0 = i - 393216;
        const float* ws = W_dec + (size_t)j0 * 8;
        u32 o[4];
#pragma unroll
        for (int j = 0; j < 4; j++) {
            u16 lo = f2bf(ws[2*j]);
            u16 hi = f2bf(ws[2*j+1]);
            o[j] = (u32)lo | ((u32)hi << 16);
        }
        *(uint4*)(Wd + (size_t)j0 * 8) = make_uint4(o[0], o[1], o[2], o[3]);
    } else {
        int j0 = i - 655360;
        if (j0 < 4096) cnt[j0] = 0;
    }
}

// ---------------------------------------------------------------------------
// Kernel 1: encode GEMM on swizzled operands (all loads coalesced); epilogue
// emits candidates (q >= QMIN) via wave-aggregated LDS staging -> one global
// atomic per (row, block) -> contiguous list writes.
// ---------------------------------------------------------------------------
__global__ __launch_bounds__(256) void encode_gemm(const u16* __restrict__ A,
                                                   const u16* __restrict__ W,
                                                   const float* __restrict__ b_enc,
                                                   u32* __restrict__ cnt,
                                                   u32* __restrict__ list) {
    const int tid  = threadIdx.x;
    const int lane = tid & 63;
    const int wave = tid >> 6;
    const int wm = wave & 1, wn = wave >> 1;
    const int bm0 = blockIdx.y * 128;             // block row base
    const int n0  = blockIdx.x * 128 + wn * 64;
    const int mt0 = (bm0 >> 4) + wm * 4;          // wave's 4 m-tiles
    const int nt0 = (n0 >> 4);                    // wave's 4 n-tiles
    const int r15 = lane & 15;

    __shared__ u32 s_n;
    __shared__ u32 s_ebuf[ECAP];   // entry: (rowl<<21)|(n<<8)|q
    __shared__ u8  s_eofs[ECAP];   // within-(row,block) offset (<128, fits u8)
    __shared__ u32 l_cnt[128];
    __shared__ u32 l_base[128];

    if (tid == 0) s_n = 0;
    if (tid < 128) l_cnt[tid] = 0;
    __syncthreads();

    f32x4 acc[4][4] = {};
    for (int kt = 0; kt < 8; kt++) {
        short8 a[4], b[4];
#pragma unroll
        for (int i = 0; i < 4; i++)
            a[i] = *(const short8*)(A + (((size_t)(mt0 + i) * 8 + kt) * 64 + lane) * 8);
#pragma unroll
        for (int j = 0; j < 4; j++)
            b[j] = *(const short8*)(W + (((size_t)(nt0 + j) * 8 + kt) * 64 + lane) * 8);
#pragma unroll
        for (int i = 0; i < 4; i++)
#pragma unroll
            for (int j = 0; j < 4; j++)
                acc[i][j] = __builtin_amdgcn_mfma_f32_16x16x32_bf16(a[i], b[j], acc[i][j], 0, 0, 0);
    }

    // C/D layout: col(n) = lane&15, row(m) = (lane>>4)*4 + reg   [m89-verified]
    float bias[4];
#pragma unroll
    for (int j = 0; j < 4; j++) bias[j] = b_enc[n0 + j * 16 + r15];

    // --- pass 1: per-thread candidate count ---------------------------------
    int my_n = 0;
#pragma unroll
    for (int j = 0; j < 4; j++)
#pragma unroll
        for (int i = 0; i < 4; i++)
#pragma unroll
            for (int rq = 0; rq < 4; rq++) {
                float v = acc[i][j][rq] + bias[j];
                my_n += ((int)(v * 32.f + 0.5f) >= QMIN);
            }

    // --- wave prefix scan + one LDS atomic per wave -------------------------
    int pv = my_n;
#pragma unroll
    for (int d = 1; d < 64; d <<= 1) {
        int t = __shfl_up(pv, d);
        if (lane >= d) pv += t;
    }
    u32 base;
    if (lane == 63) base = atomicAdd(&s_n, (u32)pv);  // lane63 pv == wave total
    base = __shfl((int)base, 63);
    u32 off = base + (u32)(pv - my_n);

    // --- pass 2: write entries at scanned offsets ---------------------------
#pragma unroll
    for (int j = 0; j < 4; j++)
#pragma unroll
        for (int i = 0; i < 4; i++) {
            int rowl0 = wm * 64 + i * 16 + (lane >> 4) * 4;   // local row
#pragma unroll
            for (int rq = 0; rq < 4; rq++) {
                float v = acc[i][j][rq] + bias[j];
                int q = (int)(v * 32.f + 0.5f);
                if (q >= QMIN) {
                    if (q > 255) q = 255;
                    u32 rowl = (u32)(rowl0 + rq);
                    int n = n0 + j * 16 + r15;
                    u32 e = (rowl << 21) | ((u32)n << 8) | (u32)q;
                    if (off < ECAP) {
                        s_ebuf[off] = e;
                    } else {                       // never expected: direct spill
                        u32 g = atomicAdd(&cnt[bm0 + rowl], 1u);
                        if (g < CAPL) list[(size_t)(bm0 + rowl) * CAPL + g] = e & 0x1FFFFFu;
                    }
                    off++;
                }
            }
        }
    __syncthreads();

    int ne = (int)s_n; if (ne > ECAP) ne = ECAP;
    // Phase A: within-row offsets via LDS atomics (spread over 128 addresses)
    for (int i = tid; i < ne; i += 256)
        s_eofs[i] = (u8)atomicAdd(&l_cnt[s_ebuf[i] >> 21], 1u);
    __syncthreads();
    // Phase B: one global reservation per (row, block)
    if (tid < 128 && l_cnt[tid] > 0)
        l_base[tid] = atomicAdd(&cnt[bm0 + tid], l_cnt[tid]);
    __syncthreads();
    // Phase C: contiguous slot writes
    for (int i = tid; i < ne; i += 256) {
        u32 e = s_ebuf[i];
        u32 rowl = e >> 21;
        u32 slot = l_base[rowl] + (u32)s_eofs[i];
        if (slot < CAPL) list[(size_t)(bm0 + rowl) * CAPL + slot] = e & 0x1FFFFFu;
    }
}

// ---------------------------------------------------------------------------
// Kernel 2: per row — list -> q-hist -> t32 -> compact refine subset
// {q >= t32-2} -> exact fp64 refine -> exact top-32 (val desc, idx asc) ->
// decode with bf16 W_dec. Cheap exact fallback (never expected).
// ---------------------------------------------------------------------------
__global__ __launch_bounds__(256) void select_decode(const u32* __restrict__ cnt,
                                                     const u32* __restrict__ list,
                                                     const float* __restrict__ x,
                                                     const float* __restrict__ W_enc,
                                                     const float* __restrict__ b_enc,
                                                     const u16* __restrict__ Wd,
                                                     const float* __restrict__ b_dec,
                                                     float* __restrict__ out) {
    const int r    = blockIdx.x;
    const int tid  = threadIdx.x;
    const int lane = tid & 63;
    const int wave = tid >> 6;
    const int grp  = tid >> 4;     // 16 groups of 16 lanes
    const int l16  = tid & 15;

    __shared__ float s_sae[256];
    __shared__ u32   hist[256];
    __shared__ int   wtot[4];
    __shared__ int   s_t32;
    __shared__ u32   s_nref;
    __shared__ int   cidx[CAPL];
    __shared__ int   cq[CAPL];
    __shared__ float cval[CAPL];
    __shared__ short rsel[RCAP];
    __shared__ float sel_val[32];
    __shared__ int   sel_idx[32];

    s_sae[tid] = x[(size_t)r * 256 + tid] - b_dec[tid];
    hist[tid] = 0;
    if (tid == 0) { s_t32 = -1; s_nref = 0; }
    if (tid < 32) { sel_val[tid] = 0.f; sel_idx[tid] = 0; }
    __syncthreads();

    auto find_t32 = [&]() {
        int c = (int)hist[tid];
        int s = c;
#pragma unroll
        for (int off = 1; off < 64; off <<= 1) {
            int v = __shfl_down(s, off);
            if (lane + off < 64) s += v;
        }
        if (lane == 0) wtot[wave] = s;
        __syncthreads();
        int hisum = 0;
        for (int ww = wave + 1; ww < 4; ww++) hisum += wtot[ww];
        int S = s + hisum;
        if (S >= 32 && (S - c) < 32) s_t32 = tid;   // unique transition bin
        __syncthreads();
    };
    auto exact_col = [&](int col) -> double {
        const float4* wr = (const float4*)(W_enc + (size_t)col * 256 + l16 * 16);
        double s = 0.0;
#pragma unroll
        for (int u = 0; u < 4; u++) {
            float4 wv = wr[u];
            const float* sp = &s_sae[l16 * 16 + u * 4];
            s += (double)wv.x * (double)sp[0] + (double)wv.y * (double)sp[1]
               + (double)wv.z * (double)sp[2] + (double)wv.w * (double)sp[3];
        }
#pragma unroll
        for (int off = 8; off; off >>= 1) s += __shfl_down(s, off, 16);
        return s;
    };

    const int m_all = (int)cnt[r];
    const int m = m_all < CAPL ? m_all : CAPL;

    // --- load candidate list, histogram q ------------------------------------
    for (int i = tid; i < m; i += 256) {
        u32 p = list[(size_t)r * CAPL + i];
        int q = (int)(p & 255u);
        cq[i] = q; cidx[i] = (int)(p >> 8);
        atomicAdd(&hist[q], 1u);
    }
    __syncthreads();
    find_t32();

    const int qref = s_t32 - 2;   // true top-32 provably within {q >= qref}
    // --- compact refine subset ----------------------------------------------
    for (int i = tid; i < m; i += 256) {
        if (cq[i] >= qref) {
            u32 p = atomicAdd(&s_nref, 1u);
            if (p < RCAP) rsel[p] = (short)i;
        }
    }
    __syncthreads();
    const int nref = (int)s_nref;

    // valid screen: no overflow anywhere, t32-2 >= QMIN (membership proof)
    const bool fb = (m_all > CAPL) || (s_t32 < QMIN + 2) || (nref > RCAP);

    if (!fb) {
        // --- exact refine (fp64): 2 candidates per 16-lane group per pass ---
        for (int t0 = 0; t0 < nref; t0 += 32) {
            int cA = t0 + grp, cB = t0 + grp + 16;
            if (cA < nref) {
                int iA = cidx[rsel[cA]];
                double s = exact_col(iA);
                if (l16 == 0) {
                    float f = (float)(s + (double)b_enc[iA]);
                    cval[rsel[cA]] = f > 0.f ? f : 0.f;
                }
            }
            if (cB < nref) {
                int iB = cidx[rsel[cB]];
                double s = exact_col(iB);
                if (l16 == 0) {
                    float f = (float)(s + (double)b_enc[iB]);
                    cval[rsel[cB]] = f > 0.f ? f : 0.f;
                }
            }
        }
        __syncthreads();

        // --- exact top-32 among refined by (val desc, idx asc) --------------
        for (int k = tid; k < nref; k += 256) {
            int ci = rsel[k];
            float vi = cval[ci];
            int   ii = cidx[ci];
            int rank = 0;
            for (int j = 0; j < nref; j++) {
                int cj = rsel[j];
                float vj = cval[cj];
                rank += (vj > vi) || (vj == vi && cidx[cj] < ii);
            }
            if (rank < 32) { sel_val[rank] = vi; sel_idx[rank] = ii; }
        }
        __syncthreads();
    } else {
        // --- cheap exact fallback: 2 streaming passes over all 8192 cols ----
        hist[tid] = 0;
        if (tid == 0) { s_t32 = -1; s_nref = 0; }
        __syncthreads();
        for (int it = 0; it < 512; it++) {
            int col = it * 16 + grp;
            double s = exact_col(col);
            if (l16 == 0) {
                float f = (float)(s + (double)b_enc[col]);
                f = f > 0.f ? f : 0.f;
                int q = (int)(f * 32.f + 0.5f); if (q > 255) q = 255;
                if (q >= 1) atomicAdd(&hist[q], 1u);
            }
        }
        __syncthreads();
        find_t32();
        int qlo = s_t32 >= 3 ? s_t32 - 2 : 1;
        for (int pass = 0; pass < 2; pass++) {
            for (int it = 0; it < 512; it++) {
                int col = it * 16 + grp;
                double s = exact_col(col);
                if (l16 == 0) {
                    float f = (float)(s + (double)b_enc[col]);
                    f = f > 0.f ? f : 0.f;
                    int q = (int)(f * 32.f + 0.5f); if (q > 255) q = 255;
                    if (q >= qlo) {
                        u32 p = atomicAdd(&s_nref, 1u);
                        if (p < CAPL) { cidx[p] = col; cval[p] = f; }
                    }
                }
            }
            __syncthreads();
            if ((int)s_nref <= CAPL) break;
            if (tid == 0) s_nref = 0;
            qlo = s_t32 > 0 ? s_t32 : 1;
            __syncthreads();
        }
        int nf = (int)s_nref; if (nf > CAPL) nf = CAPL;
        for (int k = tid; k < nf; k += 256) {
            float vi = cval[k]; int ii = cidx[k]; int rank = 0;
            for (int j = 0; j < nf; j++)
                rank += (cval[j] > vi) || (cval[j] == vi && cidx[j] < ii);
            if (rank < 32) { sel_val[rank] = vi; sel_idx[rank] = ii; }
        }
        __syncthreads();
    }

    // --- decode: out[r] = b_dec + sum_k z_k * bf16(W_dec)[idx_k] ------------
    u16 wv[32];
#pragma unroll
    for (int k = 0; k < 32; k++)
        wv[k] = Wd[(size_t)sel_idx[k] * 256 + tid];   // 32 independent loads
    float acc = b_dec[tid];
#pragma unroll
    for (int k = 0; k < 32; k++)
        acc += sel_val[k] * bf2f(wv[k]);
    out[(size_t)r * 256 + tid] = acc;
}

// ---------------------------------------------------------------------------
extern "C" void kernel_launch(void* const* d_in, const int* in_sizes, int n_in,
                              void* d_out, int out_size, void* d_ws, size_t ws_size,
                              hipStream_t stream) {
    const float* x     = (const float*)d_in[0];   // [4096,256] f32
    const float* W_enc = (const float*)d_in[1];   // [8192,256] f32
    const float* b_enc = (const float*)d_in[2];   // [8192]     f32
    const float* W_dec = (const float*)d_in[3];   // [8192,256] f32
    const float* b_dec = (const float*)d_in[4];   // [256]      f32
    float* out = (float*)d_out;                   // [4096,256] f32

    u32* cnt  = (u32*)d_ws;                          // 16 KB per-row counters
    u32* list = cnt + 4096;                          // 8 MB candidate lists
    u16* Ap   = (u16*)(list + (size_t)4096 * CAPL);  // 2 MB swizzled bf16(x-b_dec)
    u16* Wb   = Ap + (size_t)4096 * 256;             // 4 MB swizzled bf16(W_enc)
    u16* Wd   = Wb + (size_t)8192 * 256;             // 4 MB bf16(W_dec)

    prep_convert<<<2576, 256, 0, stream>>>(x, b_dec, W_enc, W_dec, Ap, Wb, Wd, cnt);
    encode_gemm<<<dim3(64, 32), 256, 0, stream>>>(Ap, Wb, b_enc, cnt, list);
    select_decode<<<4096, 256, 0, stream>>>(cnt, list, x, W_enc, b_enc, Wd, b_dec, out);
}

// Round 9
// 162.377 us; speedup vs baseline: 54.8382x; 1.0337x over previous
//
#include <hip/hip_runtime.h>

using u8  = unsigned char;
using u16 = unsigned short;
using u32 = unsigned int;
typedef __attribute__((ext_vector_type(8))) short short8;   // 8 bf16 (MFMA A/B frag)
typedef __attribute__((ext_vector_type(4))) float f32x4;    // MFMA C/D frag

#define CAPL 512   // per-row list capacity; overflow needs sigma>=1.31 (+7sd) -> never
#define QMIN 64    // static screen: q = round(32*v) >= 64  <=>  v >= 2.0
#define ECAP 1024  // per-block LDS emission buffer (expected ~373, sd ~20)
#define RCAP 128   // refine subset capacity (expected ~45, quantile-invariant)

__device__ __forceinline__ float bf2f(u16 u) {
    union { u32 i; float f; } c; c.i = ((u32)u) << 16; return c.f;
}
__device__ __forceinline__ u16 f2bf(float f) {
    union { float f; u32 i; } c; c.f = f;
    u32 u = c.i + 0x7FFFu + ((c.i >> 16) & 1u);   // RNE; inputs are finite
    return (u16)(u >> 16);
}

// ---------------------------------------------------------------------------
// Kernel 0: build FRAGMENT-SWIZZLED bf16 operands + bf16 W_dec + zero cnt.
// Swizzle: tile t=(mt*8+kt); lane l holds 8 bf16 at (row=16*mt+(l&15),
// k=32*kt+(l>>4)*8+j) stored at offset (t*64+l)*8 — frag loads are
// base+lane*16B, perfectly coalesced (1KB/wave/instruction).
// ---------------------------------------------------------------------------
__global__ __launch_bounds__(256) void prep_convert(const float* __restrict__ x,
                                                    const float* __restrict__ b_dec,
                                                    const float* __restrict__ W_enc,
                                                    const float* __restrict__ W_dec,
                                                    u16* __restrict__ Ap,
                                                    u16* __restrict__ Wb,
                                                    u16* __restrict__ Wd,
                                                    u32* __restrict__ cnt) {
    int i = blockIdx.x * 256 + threadIdx.x;     // grid = 2576 blocks exactly
    if (i < 131072) {                            // A: 256 mt x 8 kt tiles
        int lane = i & 63, t = i >> 6;
        int mt = t >> 3, kt = t & 7;
        int m = mt * 16 + (lane & 15);
        int k = kt * 32 + (lane >> 4) * 8;
        const float* xs = x + (size_t)m * 256 + k;
        const float* bd = b_dec + k;
        u32 o[4];
#pragma unroll
        for (int j = 0; j < 4; j++) {
            u16 lo = f2bf(xs[2*j]   - bd[2*j]);
            u16 hi = f2bf(xs[2*j+1] - bd[2*j+1]);
            o[j] = (u32)lo | ((u32)hi << 16);
        }
        *(uint4*)(Ap + (size_t)i * 8) = make_uint4(o[0], o[1], o[2], o[3]);
    } else if (i < 393216) {                     // W_enc: 512 nt x 8 kt tiles
        int j0 = i - 131072;
        int lane = j0 & 63, t = j0 >> 6;
        int nt = t >> 3, kt = t & 7;
        int n = nt * 16 + (lane & 15);
        int k = kt * 32 + (lane >> 4) * 8;
        const float* ws = W_enc + (size_t)n * 256 + k;
        u32 o[4];
#pragma unroll
        for (int j = 0; j < 4; j++) {
            u16 lo = f2bf(ws[2*j]);
            u16 hi = f2bf(ws[2*j+1]);
            o[j] = (u32)lo | ((u32)hi << 16);
        }
        *(uint4*)(Wb + (size_t)j0 * 8) = make_uint4(o[0], o[1], o[2], o[3]);
    } else if (i < 655360) {                     // W_dec: plain bf16, 8/thread
        int j0 = i - 393216;
        const float* ws = W_dec + (size_t)j0 * 8;
        u32 o[4];
#pragma unroll
        for (int j = 0; j < 4; j++) {
            u16 lo = f2bf(ws[2*j]);
            u16 hi = f2bf(ws[2*j+1]);
            o[j] = (u32)lo | ((u32)hi << 16);
        }
        *(uint4*)(Wd + (size_t)j0 * 8) = make_uint4(o[0], o[1], o[2], o[3]);
    } else {
        int j0 = i - 655360;
        if (j0 < 4096) cnt[j0] = 0;
    }
}

// ---------------------------------------------------------------------------
// Kernel 1: encode GEMM, 512 threads = 8 waves of 64x32 tiles (128x128 block
// tile), double-buffered register prefetch over kt so loads stay in flight
// (vmcnt>0 waits), 4 waves/SIMD occupancy. Epilogue: wave-aggregated
// candidate emission (bit-identical math to R8).
// ---------------------------------------------------------------------------
__global__ __launch_bounds__(512, 4) void encode_gemm(const u16* __restrict__ A,
                                                      const u16* __restrict__ W,
                                                      const float* __restrict__ b_enc,
                                                      u32* __restrict__ cnt,
                                                      u32* __restrict__ list) {
    const int tid  = threadIdx.x;
    const int lane = tid & 63;
    const int wave = tid >> 6;          // 0..7
    const int wm = wave & 1;            // m half (64 rows)
    const int wn = wave >> 1;           // n quarter (32 cols)
    const int bm0 = blockIdx.y * 128;   // block row base
    const int n0  = blockIdx.x * 128 + wn * 32;
    const int mt0 = blockIdx.y * 8 + wm * 4;   // wave's 4 m-tiles
    const int nt0 = blockIdx.x * 8 + wn * 2;   // wave's 2 n-tiles
    const int r15 = lane & 15;

    __shared__ u32 s_n;
    __shared__ u32 s_ebuf[ECAP];   // entry: (rowl<<21)|(n<<8)|q
    __shared__ u8  s_eofs[ECAP];   // within-(row,block) offset (<128, fits u8)
    __shared__ u32 l_cnt[128];
    __shared__ u32 l_base[128];

    if (tid == 0) s_n = 0;
    if (tid < 128) l_cnt[tid] = 0;
    __syncthreads();

    f32x4 acc[4][2] = {};
    short8 a[2][4], b[2][2];

    // preload kt=0 into buffer 0
#pragma unroll
    for (int i = 0; i < 4; i++)
        a[0][i] = *(const short8*)(A + (((size_t)(mt0 + i) * 8 + 0) * 64 + lane) * 8);
#pragma unroll
    for (int j = 0; j < 2; j++)
        b[0][j] = *(const short8*)(W + (((size_t)(nt0 + j) * 8 + 0) * 64 + lane) * 8);

#pragma unroll
    for (int kt = 0; kt < 8; kt++) {
        const int cur = kt & 1, nxt = cur ^ 1;
        if (kt < 7) {
#pragma unroll
            for (int i = 0; i < 4; i++)
                a[nxt][i] = *(const short8*)(A + (((size_t)(mt0 + i) * 8 + (kt + 1)) * 64 + lane) * 8);
#pragma unroll
            for (int j = 0; j < 2; j++)
                b[nxt][j] = *(const short8*)(W + (((size_t)(nt0 + j) * 8 + (kt + 1)) * 64 + lane) * 8);
        }
#pragma unroll
        for (int i = 0; i < 4; i++)
#pragma unroll
            for (int j = 0; j < 2; j++)
                acc[i][j] = __builtin_amdgcn_mfma_f32_16x16x32_bf16(a[cur][i], b[cur][j], acc[i][j], 0, 0, 0);
    }

    // C/D layout: col(n) = lane&15, row(m) = (lane>>4)*4 + reg   [m89-verified]
    float bias[2];
#pragma unroll
    for (int j = 0; j < 2; j++) bias[j] = b_enc[n0 + j * 16 + r15];

    // --- pass 1: per-thread candidate count ---------------------------------
    int my_n = 0;
#pragma unroll
    for (int j = 0; j < 2; j++)
#pragma unroll
        for (int i = 0; i < 4; i++)
#pragma unroll
            for (int rq = 0; rq < 4; rq++) {
                float v = acc[i][j][rq] + bias[j];
                my_n += ((int)(v * 32.f + 0.5f) >= QMIN);
            }

    // --- wave prefix scan + one LDS atomic per wave -------------------------
    int pv = my_n;
#pragma unroll
    for (int d = 1; d < 64; d <<= 1) {
        int t = __shfl_up(pv, d);
        if (lane >= d) pv += t;
    }
    u32 base;
    if (lane == 63) base = atomicAdd(&s_n, (u32)pv);  // lane63 pv == wave total
    base = __shfl((int)base, 63);
    u32 off = base + (u32)(pv - my_n);

    // --- pass 2: write entries at scanned offsets ---------------------------
#pragma unroll
    for (int j = 0; j < 2; j++)
#pragma unroll
        for (int i = 0; i < 4; i++) {
            int rowl0 = wm * 64 + i * 16 + (lane >> 4) * 4;   // local row
#pragma unroll
            for (int rq = 0; rq < 4; rq++) {
                float v = acc[i][j][rq] + bias[j];
                int q = (int)(v * 32.f + 0.5f);
                if (q >= QMIN) {
                    if (q > 255) q = 255;
                    u32 rowl = (u32)(rowl0 + rq);
                    int n = n0 + j * 16 + r15;
                    u32 e = (rowl << 21) | ((u32)n << 8) | (u32)q;
                    if (off < ECAP) {
                        s_ebuf[off] = e;
                    } else {                       // never expected: direct spill
                        u32 g = atomicAdd(&cnt[bm0 + rowl], 1u);
                        if (g < CAPL) list[(size_t)(bm0 + rowl) * CAPL + g] = e & 0x1FFFFFu;
                    }
                    off++;
                }
            }
        }
    __syncthreads();

    int ne = (int)s_n; if (ne > ECAP) ne = ECAP;
    // Phase A: within-row offsets via LDS atomics (spread over 128 addresses)
    for (int i = tid; i < ne; i += 512)
        s_eofs[i] = (u8)atomicAdd(&l_cnt[s_ebuf[i] >> 21], 1u);
    __syncthreads();
    // Phase B: one global reservation per (row, block)
    if (tid < 128 && l_cnt[tid] > 0)
        l_base[tid] = atomicAdd(&cnt[bm0 + tid], l_cnt[tid]);
    __syncthreads();
    // Phase C: contiguous slot writes
    for (int i = tid; i < ne; i += 512) {
        u32 e = s_ebuf[i];
        u32 rowl = e >> 21;
        u32 slot = l_base[rowl] + (u32)s_eofs[i];
        if (slot < CAPL) list[(size_t)(bm0 + rowl) * CAPL + slot] = e & 0x1FFFFFu;
    }
}

// ---------------------------------------------------------------------------
// Kernel 2: per row — list -> q-hist -> t32 -> compact refine subset
// {q >= t32-2} -> exact fp64 refine -> exact top-32 (val desc, idx asc) ->
// decode with bf16 W_dec. Cheap exact fallback (never expected).
// ---------------------------------------------------------------------------
__global__ __launch_bounds__(256) void select_decode(const u32* __restrict__ cnt,
                                                     const u32* __restrict__ list,
                                                     const float* __restrict__ x,
                                                     const float* __restrict__ W_enc,
                                                     const float* __restrict__ b_enc,
                                                     const u16* __restrict__ Wd,
                                                     const float* __restrict__ b_dec,
                                                     float* __restrict__ out) {
    const int r    = blockIdx.x;
    const int tid  = threadIdx.x;
    const int lane = tid & 63;
    const int wave = tid >> 6;
    const int grp  = tid >> 4;     // 16 groups of 16 lanes
    const int l16  = tid & 15;

    __shared__ float s_sae[256];
    __shared__ u32   hist[256];
    __shared__ int   wtot[4];
    __shared__ int   s_t32;
    __shared__ u32   s_nref;
    __shared__ int   cidx[CAPL];
    __shared__ int   cq[CAPL];
    __shared__ float cval[CAPL];
    __shared__ short rsel[RCAP];
    __shared__ float sel_val[32];
    __shared__ int   sel_idx[32];

    s_sae[tid] = x[(size_t)r * 256 + tid] - b_dec[tid];
    hist[tid] = 0;
    if (tid == 0) { s_t32 = -1; s_nref = 0; }
    if (tid < 32) { sel_val[tid] = 0.f; sel_idx[tid] = 0; }
    __syncthreads();

    auto find_t32 = [&]() {
        int c = (int)hist[tid];
        int s = c;
#pragma unroll
        for (int off = 1; off < 64; off <<= 1) {
            int v = __shfl_down(s, off);
            if (lane + off < 64) s += v;
        }
        if (lane == 0) wtot[wave] = s;
        __syncthreads();
        int hisum = 0;
        for (int ww = wave + 1; ww < 4; ww++) hisum += wtot[ww];
        int S = s + hisum;
        if (S >= 32 && (S - c) < 32) s_t32 = tid;   // unique transition bin
        __syncthreads();
    };
    auto exact_col = [&](int col) -> double {
        const float4* wr = (const float4*)(W_enc + (size_t)col * 256 + l16 * 16);
        double s = 0.0;
#pragma unroll
        for (int u = 0; u < 4; u++) {
            float4 wv = wr[u];
            const float* sp = &s_sae[l16 * 16 + u * 4];
            s += (double)wv.x * (double)sp[0] + (double)wv.y * (double)sp[1]
               + (double)wv.z * (double)sp[2] + (double)wv.w * (double)sp[3];
        }
#pragma unroll
        for (int off = 8; off; off >>= 1) s += __shfl_down(s, off, 16);
        return s;
    };

    const int m_all = (int)cnt[r];
    const int m = m_all < CAPL ? m_all : CAPL;

    // --- load candidate list, histogram q ------------------------------------
    for (int i = tid; i < m; i += 256) {
        u32 p = list[(size_t)r * CAPL + i];
        int q = (int)(p & 255u);
        cq[i] = q; cidx[i] = (int)(p >> 8);
        atomicAdd(&hist[q], 1u);
    }
    __syncthreads();
    find_t32();

    const int qref = s_t32 - 2;   // true top-32 provably within {q >= qref}
    // --- compact refine subset ----------------------------------------------
    for (int i = tid; i < m; i += 256) {
        if (cq[i] >= qref) {
            u32 p = atomicAdd(&s_nref, 1u);
            if (p < RCAP) rsel[p] = (short)i;
        }
    }
    __syncthreads();
    const int nref = (int)s_nref;

    // valid screen: no overflow anywhere, t32-2 >= QMIN (membership proof)
    const bool fb = (m_all > CAPL) || (s_t32 < QMIN + 2) || (nref > RCAP);

    if (!fb) {
        // --- exact refine (fp64): 2 candidates per 16-lane group per pass ---
        for (int t0 = 0; t0 < nref; t0 += 32) {
            int cA = t0 + grp, cB = t0 + grp + 16;
            if (cA < nref) {
                int iA = cidx[rsel[cA]];
                double s = exact_col(iA);
                if (l16 == 0) {
                    float f = (float)(s + (double)b_enc[iA]);
                    cval[rsel[cA]] = f > 0.f ? f : 0.f;
                }
            }
            if (cB < nref) {
                int iB = cidx[rsel[cB]];
                double s = exact_col(iB);
                if (l16 == 0) {
                    float f = (float)(s + (double)b_enc[iB]);
                    cval[rsel[cB]] = f > 0.f ? f : 0.f;
                }
            }
        }
        __syncthreads();

        // --- exact top-32 among refined by (val desc, idx asc) --------------
        for (int k = tid; k < nref; k += 256) {
            int ci = rsel[k];
            float vi = cval[ci];
            int   ii = cidx[ci];
            int rank = 0;
            for (int j = 0; j < nref; j++) {
                int cj = rsel[j];
                float vj = cval[cj];
                rank += (vj > vi) || (vj == vi && cidx[cj] < ii);
            }
            if (rank < 32) { sel_val[rank] = vi; sel_idx[rank] = ii; }
        }
        __syncthreads();
    } else {
        // --- cheap exact fallback: 2 streaming passes over all 8192 cols ----
        hist[tid] = 0;
        if (tid == 0) { s_t32 = -1; s_nref = 0; }
        __syncthreads();
        for (int it = 0; it < 512; it++) {
            int col = it * 16 + grp;
            double s = exact_col(col);
            if (l16 == 0) {
                float f = (float)(s + (double)b_enc[col]);
                f = f > 0.f ? f : 0.f;
                int q = (int)(f * 32.f + 0.5f); if (q > 255) q = 255;
                if (q >= 1) atomicAdd(&hist[q], 1u);
            }
        }
        __syncthreads();
        find_t32();
        int qlo = s_t32 >= 3 ? s_t32 - 2 : 1;
        for (int pass = 0; pass < 2; pass++) {
            for (int it = 0; it < 512; it++) {
                int col = it * 16 + grp;
                double s = exact_col(col);
                if (l16 == 0) {
                    float f = (float)(s + (double)b_enc[col]);
                    f = f > 0.f ? f : 0.f;
                    int q = (int)(f * 32.f + 0.5f); if (q > 255) q = 255;
                    if (q >= qlo) {
                        u32 p = atomicAdd(&s_nref, 1u);
                        if (p < CAPL) { cidx[p] = col; cval[p] = f; }
                    }
                }
            }
            __syncthreads();
            if ((int)s_nref <= CAPL) break;
            if (tid == 0) s_nref = 0;
            qlo = s_t32 > 0 ? s_t32 : 1;
            __syncthreads();
        }
        int nf = (int)s_nref; if (nf > CAPL) nf = CAPL;
        for (int k = tid; k < nf; k += 256) {
            float vi = cval[k]; int ii = cidx[k]; int rank = 0;
            for (int j = 0; j < nf; j++)
                rank += (cval[j] > vi) || (cval[j] == vi && cidx[j] < ii);
            if (rank < 32) { sel_val[rank] = vi; sel_idx[rank] = ii; }
        }
        __syncthreads();
    }

    // --- decode: out[r] = b_dec + sum_k z_k * bf16(W_dec)[idx_k] ------------
    u16 wv[32];
#pragma unroll
    for (int k = 0; k < 32; k++)
        wv[k] = Wd[(size_t)sel_idx[k] * 256 + tid];   // 32 independent loads
    float acc = b_dec[tid];
#pragma unroll
    for (int k = 0; k < 32; k++)
        acc += sel_val[k] * bf2f(wv[k]);
    out[(size_t)r * 256 + tid] = acc;
}

// ---------------------------------------------------------------------------
extern "C" void kernel_launch(void* const* d_in, const int* in_sizes, int n_in,
                              void* d_out, int out_size, void* d_ws, size_t ws_size,
                              hipStream_t stream) {
    const float* x     = (const float*)d_in[0];   // [4096,256] f32
    const float* W_enc = (const float*)d_in[1];   // [8192,256] f32
    const float* b_enc = (const float*)d_in[2];   // [8192]     f32
    const float* W_dec = (const float*)d_in[3];   // [8192,256] f32
    const float* b_dec = (const float*)d_in[4];   // [256]      f32
    float* out = (float*)d_out;                   // [4096,256] f32

    u32* cnt  = (u32*)d_ws;                          // 16 KB per-row counters
    u32* list = cnt + 4096;                          // 8 MB candidate lists
    u16* Ap   = (u16*)(list + (size_t)4096 * CAPL);  // 2 MB swizzled bf16(x-b_dec)
    u16* Wb   = Ap + (size_t)4096 * 256;             // 4 MB swizzled bf16(W_enc)
    u16* Wd   = Wb + (size_t)8192 * 256;             // 4 MB bf16(W_dec)

    prep_convert<<<2576, 256, 0, stream>>>(x, b_dec, W_enc, W_dec, Ap, Wb, Wd, cnt);
    encode_gemm<<<dim3(64, 32), 512, 0, stream>>>(Ap, Wb, b_enc, cnt, list);
    select_decode<<<4096, 256, 0, stream>>>(cnt, list, x, W_enc, b_enc, Wd, b_dec, out);
}

// Round 10
// 153.564 us; speedup vs baseline: 57.9855x; 1.0574x over previous
//
#include <hip/hip_runtime.h>

using u8  = unsigned char;
using u16 = unsigned short;
using u32 = unsigned int;
typedef __attribute__((ext_vector_type(8))) short short8;   // 8 bf16 (MFMA A/B frag)
typedef __attribute__((ext_vector_type(4))) float f32x4;    // MFMA C/D frag

#define CAPL 512   // per-row list capacity; overflow needs sigma>=1.31 (+7sd) -> never
#define QMIN 64    // static screen: q = round(32*v) >= 64  <=>  v >= 2.0
#define ECAP 1024  // per-block LDS emission buffer (expected ~373, sd ~20)
#define RCAP 128   // refine subset capacity (expected ~45, quantile-invariant)

#define AS1 __attribute__((address_space(1)))
#define AS3 __attribute__((address_space(3)))

__device__ __forceinline__ float bf2f(u16 u) {
    union { u32 i; float f; } c; c.i = ((u32)u) << 16; return c.f;
}
__device__ __forceinline__ u16 f2bf(float f) {
    union { float f; u32 i; } c; c.f = f;
    u32 u = c.i + 0x7FFFu + ((c.i >> 16) & 1u);   // RNE; inputs are finite
    return (u16)(u >> 16);
}

// ---------------------------------------------------------------------------
// Kernel 0: build FRAGMENT-SWIZZLED bf16 operands + bf16 W_dec + zero cnt.
// Swizzle: tile t=(mt*8+kt); lane l holds 8 bf16 at (row=16*mt+(l&15),
// k=32*kt+(l>>4)*8+j) stored at offset (t*64+l)*8 — one tile = 1 KB
// contiguous = one global_load_lds_dwordx4 per wave.
// ---------------------------------------------------------------------------
__global__ __launch_bounds__(256) void prep_convert(const float* __restrict__ x,
                                                    const float* __restrict__ b_dec,
                                                    const float* __restrict__ W_enc,
                                                    const float* __restrict__ W_dec,
                                                    u16* __restrict__ Ap,
                                                    u16* __restrict__ Wb,
                                                    u16* __restrict__ Wd,
                                                    u32* __restrict__ cnt) {
    int i = blockIdx.x * 256 + threadIdx.x;     // grid = 2576 blocks exactly
    if (i < 131072) {                            // A: 256 mt x 8 kt tiles
        int lane = i & 63, t = i >> 6;
        int mt = t >> 3, kt = t & 7;
        int m = mt * 16 + (lane & 15);
        int k = kt * 32 + (lane >> 4) * 8;
        const float* xs = x + (size_t)m * 256 + k;
        const float* bd = b_dec + k;
        u32 o[4];
#pragma unroll
        for (int j = 0; j < 4; j++) {
            u16 lo = f2bf(xs[2*j]   - bd[2*j]);
            u16 hi = f2bf(xs[2*j+1] - bd[2*j+1]);
            o[j] = (u32)lo | ((u32)hi << 16);
        }
        *(uint4*)(Ap + (size_t)i * 8) = make_uint4(o[0], o[1], o[2], o[3]);
    } else if (i < 393216) {                     // W_enc: 512 nt x 8 kt tiles
        int j0 = i - 131072;
        int lane = j0 & 63, t = j0 >> 6;
        int nt = t >> 3, kt = t & 7;
        int n = nt * 16 + (lane & 15);
        int k = kt * 32 + (lane >> 4) * 8;
        const float* ws = W_enc + (size_t)n * 256 + k;
        u32 o[4];
#pragma unroll
        for (int j = 0; j < 4; j++) {
            u16 lo = f2bf(ws[2*j]);
            u16 hi = f2bf(ws[2*j+1]);
            o[j] = (u32)lo | ((u32)hi << 16);
        }
        *(uint4*)(Wb + (size_t)j0 * 8) = make_uint4(o[0], o[1], o[2], o[3]);
    } else if (i < 655360) {                     // W_dec: plain bf16, 8/thread
        int j0 = i - 393216;
        const float* ws = W_dec + (size_t)j0 * 8;
        u32 o[4];
#pragma unroll
        for (int j = 0; j < 4; j++) {
            u16 lo = f2bf(ws[2*j]);
            u16 hi = f2bf(ws[2*j+1]);
            o[j] = (u32)lo | ((u32)hi << 16);
        }
        *(uint4*)(Wd + (size_t)j0 * 8) = make_uint4(o[0], o[1], o[2], o[3]);
    } else {
        int j0 = i - 655360;
        if (j0 < 4096) cnt[j0] = 0;
    }
}

// ---------------------------------------------------------------------------
// Kernel 1: encode GEMM, 256 threads = 4 waves of 64x64 tiles (128x128 block
// tile). Double-buffered LDS staging via global_load_lds width=16: per kt,
// 16 tiles (8 A + 8 B, 1 KB each) staged once per block, fragments from
// ds_read_b128. Each operand byte crosses the TA path once per block
// (128 KB) instead of 2-4x (384 KB) — removes the L1-return bottleneck.
// Epilogue: wave-aggregated candidate emission (bit-identical math).
// ---------------------------------------------------------------------------
__global__ __launch_bounds__(256, 4) void encode_gemm(const u16* __restrict__ A,
                                                      const u16* __restrict__ W,
                                                      const float* __restrict__ b_enc,
                                                      u32* __restrict__ cnt,
                                                      u32* __restrict__ list) {
    const int tid  = threadIdx.x;
    const int lane = tid & 63;
    const int wave = tid >> 6;          // 0..3
    const int wm = wave & 1, wn = wave >> 1;
    const int bm0 = blockIdx.y * 128;   // block row base
    const int n0  = blockIdx.x * 128 + wn * 64;
    const int mtb = blockIdx.y * 8;     // block's first m-tile
    const int ntb = blockIdx.x * 8;     // block's first n-tile
    const int r15 = lane & 15;

    __shared__ u16 stg[2][16][512];     // 32 KB double-buffered staging
    __shared__ u32 s_n;
    __shared__ u32 s_ebuf[ECAP];        // entry: (rowl<<21)|(n<<8)|q
    __shared__ u8  s_eofs[ECAP];        // within-(row,block) offset (<128)
    __shared__ u32 l_cnt[128];
    __shared__ u32 l_base[128];

    if (tid == 0) s_n = 0;
    if (tid < 128) l_cnt[tid] = 0;

    // stage 4 tiles (slot = wave*4 + s2) of K-chunk kt into stg[buf]:
    // slots 0-7 = A m-tiles, 8-15 = B n-tiles. One dwordx4 direct-to-LDS
    // per wave per tile: HW writes lane's 16B at uniform base + lane*16.
    auto stage = [&](int buf, int kt) {
#pragma unroll
        for (int s2 = 0; s2 < 4; s2++) {
            int slot = wave * 4 + s2;
            const u16* g = (slot < 8)
                ? A + ((size_t)((mtb + slot) * 8 + kt) * 64 + lane) * 8
                : W + ((size_t)((ntb + (slot - 8)) * 8 + kt) * 64 + lane) * 8;
            __builtin_amdgcn_global_load_lds((const AS1 u32*)(const void*)g,
                                             (AS3 u32*)(void*)&stg[buf][slot][0],
                                             16, 0, 0);
        }
    };

    f32x4 acc[4][4] = {};
    stage(0, 0);
    __syncthreads();    // drains staging (vmcnt 0) + covers l_cnt init

#pragma unroll
    for (int kt = 0; kt < 8; kt++) {
        const int cur = kt & 1, nxt = cur ^ 1;
        if (kt < 7) stage(nxt, kt + 1);     // async, in flight across MFMA
        short8 a[4], b[4];
#pragma unroll
        for (int i = 0; i < 4; i++)
            a[i] = *(const short8*)&stg[cur][wm * 4 + i][lane * 8];
#pragma unroll
        for (int j = 0; j < 4; j++)
            b[j] = *(const short8*)&stg[cur][8 + wn * 4 + j][lane * 8];
#pragma unroll
        for (int i = 0; i < 4; i++)
#pragma unroll
            for (int j = 0; j < 4; j++)
                acc[i][j] = __builtin_amdgcn_mfma_f32_16x16x32_bf16(a[i], b[j], acc[i][j], 0, 0, 0);
        __syncthreads();   // next buf ready; cur consumed by all waves
    }

    // C/D layout: col(n) = lane&15, row(m) = (lane>>4)*4 + reg   [m89-verified]
    float bias[4];
#pragma unroll
    for (int j = 0; j < 4; j++) bias[j] = b_enc[n0 + j * 16 + r15];

    // --- pass 1: per-thread candidate count ---------------------------------
    int my_n = 0;
#pragma unroll
    for (int j = 0; j < 4; j++)
#pragma unroll
        for (int i = 0; i < 4; i++)
#pragma unroll
            for (int rq = 0; rq < 4; rq++) {
                float v = acc[i][j][rq] + bias[j];
                my_n += ((int)(v * 32.f + 0.5f) >= QMIN);
            }

    // --- wave prefix scan + one LDS atomic per wave -------------------------
    int pv = my_n;
#pragma unroll
    for (int d = 1; d < 64; d <<= 1) {
        int t = __shfl_up(pv, d);
        if (lane >= d) pv += t;
    }
    u32 base;
    if (lane == 63) base = atomicAdd(&s_n, (u32)pv);  // lane63 pv == wave total
    base = __shfl((int)base, 63);
    u32 off = base + (u32)(pv - my_n);

    // --- pass 2: write entries at scanned offsets ---------------------------
#pragma unroll
    for (int j = 0; j < 4; j++)
#pragma unroll
        for (int i = 0; i < 4; i++) {
            int rowl0 = wm * 64 + i * 16 + (lane >> 4) * 4;   // local row
#pragma unroll
            for (int rq = 0; rq < 4; rq++) {
                float v = acc[i][j][rq] + bias[j];
                int q = (int)(v * 32.f + 0.5f);
                if (q >= QMIN) {
                    if (q > 255) q = 255;
                    u32 rowl = (u32)(rowl0 + rq);
                    int n = n0 + j * 16 + r15;
                    u32 e = (rowl << 21) | ((u32)n << 8) | (u32)q;
                    if (off < ECAP) {
                        s_ebuf[off] = e;
                    } else {                       // never expected: direct spill
                        u32 g = atomicAdd(&cnt[bm0 + rowl], 1u);
                        if (g < CAPL) list[(size_t)(bm0 + rowl) * CAPL + g] = e & 0x1FFFFFu;
                    }
                    off++;
                }
            }
        }
    __syncthreads();

    int ne = (int)s_n; if (ne > ECAP) ne = ECAP;
    // Phase A: within-row offsets via LDS atomics (spread over 128 addresses)
    for (int i = tid; i < ne; i += 256)
        s_eofs[i] = (u8)atomicAdd(&l_cnt[s_ebuf[i] >> 21], 1u);
    __syncthreads();
    // Phase B: one global reservation per (row, block)
    if (tid < 128 && l_cnt[tid] > 0)
        l_base[tid] = atomicAdd(&cnt[bm0 + tid], l_cnt[tid]);
    __syncthreads();
    // Phase C: contiguous slot writes
    for (int i = tid; i < ne; i += 256) {
        u32 e = s_ebuf[i];
        u32 rowl = e >> 21;
        u32 slot = l_base[rowl] + (u32)s_eofs[i];
        if (slot < CAPL) list[(size_t)(bm0 + rowl) * CAPL + slot] = e & 0x1FFFFFu;
    }
}

// ---------------------------------------------------------------------------
// Kernel 2: per row — list -> q-hist -> t32 -> compact refine subset
// {q >= t32-2} -> exact fp64 refine -> exact top-32 (val desc, idx asc) ->
// decode with bf16 W_dec. Cheap exact fallback (never expected).
// ---------------------------------------------------------------------------
__global__ __launch_bounds__(256) void select_decode(const u32* __restrict__ cnt,
                                                     const u32* __restrict__ list,
                                                     const float* __restrict__ x,
                                                     const float* __restrict__ W_enc,
                                                     const float* __restrict__ b_enc,
                                                     const u16* __restrict__ Wd,
                                                     const float* __restrict__ b_dec,
                                                     float* __restrict__ out) {
    const int r    = blockIdx.x;
    const int tid  = threadIdx.x;
    const int lane = tid & 63;
    const int wave = tid >> 6;
    const int grp  = tid >> 4;     // 16 groups of 16 lanes
    const int l16  = tid & 15;

    __shared__ float s_sae[256];
    __shared__ u32   hist[256];
    __shared__ int   wtot[4];
    __shared__ int   s_t32;
    __shared__ u32   s_nref;
    __shared__ int   cidx[CAPL];
    __shared__ int   cq[CAPL];
    __shared__ float cval[CAPL];
    __shared__ short rsel[RCAP];
    __shared__ float sel_val[32];
    __shared__ int   sel_idx[32];

    s_sae[tid] = x[(size_t)r * 256 + tid] - b_dec[tid];
    hist[tid] = 0;
    if (tid == 0) { s_t32 = -1; s_nref = 0; }
    if (tid < 32) { sel_val[tid] = 0.f; sel_idx[tid] = 0; }
    __syncthreads();

    auto find_t32 = [&]() {
        int c = (int)hist[tid];
        int s = c;
#pragma unroll
        for (int off = 1; off < 64; off <<= 1) {
            int v = __shfl_down(s, off);
            if (lane + off < 64) s += v;
        }
        if (lane == 0) wtot[wave] = s;
        __syncthreads();
        int hisum = 0;
        for (int ww = wave + 1; ww < 4; ww++) hisum += wtot[ww];
        int S = s + hisum;
        if (S >= 32 && (S - c) < 32) s_t32 = tid;   // unique transition bin
        __syncthreads();
    };
    auto exact_col = [&](int col) -> double {
        const float4* wr = (const float4*)(W_enc + (size_t)col * 256 + l16 * 16);
        double s = 0.0;
#pragma unroll
        for (int u = 0; u < 4; u++) {
            float4 wv = wr[u];
            const float* sp = &s_sae[l16 * 16 + u * 4];
            s += (double)wv.x * (double)sp[0] + (double)wv.y * (double)sp[1]
               + (double)wv.z * (double)sp[2] + (double)wv.w * (double)sp[3];
        }
#pragma unroll
        for (int off = 8; off; off >>= 1) s += __shfl_down(s, off, 16);
        return s;
    };

    const int m_all = (int)cnt[r];
    const int m = m_all < CAPL ? m_all : CAPL;

    // --- load candidate list, histogram q ------------------------------------
    for (int i = tid; i < m; i += 256) {
        u32 p = list[(size_t)r * CAPL + i];
        int q = (int)(p & 255u);
        cq[i] = q; cidx[i] = (int)(p >> 8);
        atomicAdd(&hist[q], 1u);
    }
    __syncthreads();
    find_t32();

    const int qref = s_t32 - 2;   // true top-32 provably within {q >= qref}
    // --- compact refine subset ----------------------------------------------
    for (int i = tid; i < m; i += 256) {
        if (cq[i] >= qref) {
            u32 p = atomicAdd(&s_nref, 1u);
            if (p < RCAP) rsel[p] = (short)i;
        }
    }
    __syncthreads();
    const int nref = (int)s_nref;

    // valid screen: no overflow anywhere, t32-2 >= QMIN (membership proof)
    const bool fb = (m_all > CAPL) || (s_t32 < QMIN + 2) || (nref > RCAP);

    if (!fb) {
        // --- exact refine (fp64): 2 candidates per 16-lane group per pass ---
        for (int t0 = 0; t0 < nref; t0 += 32) {
            int cA = t0 + grp, cB = t0 + grp + 16;
            if (cA < nref) {
                int iA = cidx[rsel[cA]];
                double s = exact_col(iA);
                if (l16 == 0) {
                    float f = (float)(s + (double)b_enc[iA]);
                    cval[rsel[cA]] = f > 0.f ? f : 0.f;
                }
            }
            if (cB < nref) {
                int iB = cidx[rsel[cB]];
                double s = exact_col(iB);
                if (l16 == 0) {
                    float f = (float)(s + (double)b_enc[iB]);
                    cval[rsel[cB]] = f > 0.f ? f : 0.f;
                }
            }
        }
        __syncthreads();

        // --- exact top-32 among refined by (val desc, idx asc) --------------
        for (int k = tid; k < nref; k += 256) {
            int ci = rsel[k];
            float vi = cval[ci];
            int   ii = cidx[ci];
            int rank = 0;
            for (int j = 0; j < nref; j++) {
                int cj = rsel[j];
                float vj = cval[cj];
                rank += (vj > vi) || (vj == vi && cidx[cj] < ii);
            }
            if (rank < 32) { sel_val[rank] = vi; sel_idx[rank] = ii; }
        }
        __syncthreads();
    } else {
        // --- cheap exact fallback: 2 streaming passes over all 8192 cols ----
        hist[tid] = 0;
        if (tid == 0) { s_t32 = -1; s_nref = 0; }
        __syncthreads();
        for (int it = 0; it < 512; it++) {
            int col = it * 16 + grp;
            double s = exact_col(col);
            if (l16 == 0) {
                float f = (float)(s + (double)b_enc[col]);
                f = f > 0.f ? f : 0.f;
                int q = (int)(f * 32.f + 0.5f); if (q > 255) q = 255;
                if (q >= 1) atomicAdd(&hist[q], 1u);
            }
        }
        __syncthreads();
        find_t32();
        int qlo = s_t32 >= 3 ? s_t32 - 2 : 1;
        for (int pass = 0; pass < 2; pass++) {
            for (int it = 0; it < 512; it++) {
                int col = it * 16 + grp;
                double s = exact_col(col);
                if (l16 == 0) {
                    float f = (float)(s + (double)b_enc[col]);
                    f = f > 0.f ? f : 0.f;
                    int q = (int)(f * 32.f + 0.5f); if (q > 255) q = 255;
                    if (q >= qlo) {
                        u32 p = atomicAdd(&s_nref, 1u);
                        if (p < CAPL) { cidx[p] = col; cval[p] = f; }
                    }
                }
            }
            __syncthreads();
            if ((int)s_nref <= CAPL) break;
            if (tid == 0) s_nref = 0;
            qlo = s_t32 > 0 ? s_t32 : 1;
            __syncthreads();
        }
        int nf = (int)s_nref; if (nf > CAPL) nf = CAPL;
        for (int k = tid; k < nf; k += 256) {
            float vi = cval[k]; int ii = cidx[k]; int rank = 0;
            for (int j = 0; j < nf; j++)
                rank += (cval[j] > vi) || (cval[j] == vi && cidx[j] < ii);
            if (rank < 32) { sel_val[rank] = vi; sel_idx[rank] = ii; }
        }
        __syncthreads();
    }

    // --- decode: out[r] = b_dec + sum_k z_k * bf16(W_dec)[idx_k] ------------
    u16 wv[32];
#pragma unroll
    for (int k = 0; k < 32; k++)
        wv[k] = Wd[(size_t)sel_idx[k] * 256 + tid];   // 32 independent loads
    float acc = b_dec[tid];
#pragma unroll
    for (int k = 0; k < 32; k++)
        acc += sel_val[k] * bf2f(wv[k]);
    out[(size_t)r * 256 + tid] = acc;
}

// ---------------------------------------------------------------------------
extern "C" void kernel_launch(void* const* d_in, const int* in_sizes, int n_in,
                              void* d_out, int out_size, void* d_ws, size_t ws_size,
                              hipStream_t stream) {
    const float* x     = (const float*)d_in[0];   // [4096,256] f32
    const float* W_enc = (const float*)d_in[1];   // [8192,256] f32
    const float* b_enc = (const float*)d_in[2];   // [8192]     f32
    const float* W_dec = (const float*)d_in[3];   // [8192,256] f32
    const float* b_dec = (const float*)d_in[4];   // [256]      f32
    float* out = (float*)d_out;                   // [4096,256] f32

    u32* cnt  = (u32*)d_ws;                          // 16 KB per-row counters
    u32* list = cnt + 4096;                          // 8 MB candidate lists
    u16* Ap   = (u16*)(list + (size_t)4096 * CAPL);  // 2 MB swizzled bf16(x-b_dec)
    u16* Wb   = Ap + (size_t)4096 * 256;             // 4 MB swizzled bf16(W_enc)
    u16* Wd   = Wb + (size_t)8192 * 256;             // 4 MB bf16(W_dec)

    prep_convert<<<2576, 256, 0, stream>>>(x, b_dec, W_enc, W_dec, Ap, Wb, Wd, cnt);
    encode_gemm<<<dim3(64, 32), 256, 0, stream>>>(Ap, Wb, b_enc, cnt, list);
    select_decode<<<4096, 256, 0, stream>>>(cnt, list, x, W_enc, b_enc, Wd, b_dec, out);
}